// Round 1
// baseline (1520.015 us; speedup 1.0000x reference)
//
#include <hip/hip_runtime.h>

#define N_NODES 20000
#define N_EDGES 400000
#define NCH 64
#define NLM 16      // (LMAX+1)^2
#define NELEM 10
#define INV_AVG (1.0f / 20.0f)

// ---------------- K1: nf = node_feats @ W_up ----------------
__global__ void __launch_bounds__(256) k_linear_up(
    const float* __restrict__ node_feats,
    const float* __restrict__ W_up,
    float* __restrict__ nf)
{
    __shared__ float Ws[64 * 64];
    int tid = threadIdx.x;
    for (int i = tid; i < 64 * 64; i += 256) Ws[i] = W_up[i];
    __syncthreads();
    int n = blockIdx.x * 4 + (tid >> 6);
    if (n >= N_NODES) return;
    int c = tid & 63;
    const float* row = node_feats + n * 64;
    float acc = 0.f;
#pragma unroll
    for (int k = 0; k < 64; ++k) acc += row[k] * Ws[k * 64 + c];
    nf[n * 64 + c] = acc;
}

// ---------------- K2: edge message + scatter (atomics into d_out) ----------------
__global__ void __launch_bounds__(256) k_edge_scatter(
    const float* __restrict__ nf,
    const float* __restrict__ edge_attrs,   // (E,16)
    const float* __restrict__ edge_feats,   // (E,256)
    const int* __restrict__ sender,
    const int* __restrict__ receiver,
    float* __restrict__ msg)                // (N,16,64) == d_out
{
    int tid = threadIdx.x;
    int e = blockIdx.x * 4 + (tid >> 6);
    if (e >= N_EDGES) return;
    int lane = tid & 63;
    int s = sender[e];
    int r = receiver[e];

    float sfv = nf[s * 64 + lane];
    float prod[4];
#pragma unroll
    for (int l = 0; l < 4; ++l)
        prod[l] = sfv * edge_feats[e * 256 + l * 64 + lane];

    // lane (c&15) holds sh[c&15]; broadcast via shfl
    float shv = edge_attrs[e * 16 + (lane & 15)];
    float* outr = msg + (size_t)r * 1024;
#pragma unroll
    for (int lm = 0; lm < 16; ++lm) {
        int l = (lm >= 9) ? 3 : (lm >= 4) ? 2 : (lm >= 1) ? 1 : 0;
        float sh_lm = __shfl(shv, lm, 64);
        atomicAdd(&outr[lm * 64 + lane], sh_lm * prod[l]);
    }
}

// ---------------- K3: W_comb[z,l] = W_lin[l] @ W_skip[z,l] / 20 ----------------
__global__ void __launch_bounds__(256) k_wcomb(
    const float* __restrict__ W_lin,   // (4,64,64)
    const float* __restrict__ W_skip,  // (10,4,64,64)
    float* __restrict__ W_comb)        // (10,4,64,64)
{
    __shared__ float A[64 * 64];
    __shared__ float B[64 * 64];
    int zl = blockIdx.x;           // z*4 + l
    int l = zl & 3;
    int tid = threadIdx.x;
    for (int i = tid; i < 4096; i += 256) {
        A[i] = W_lin[l * 4096 + i];
        B[i] = W_skip[zl * 4096 + i];
    }
    __syncthreads();
    for (int i = tid; i < 4096; i += 256) {
        int k = i >> 6, d = i & 63;
        float acc = 0.f;
#pragma unroll
        for (int c = 0; c < 64; ++c) acc += A[k * 64 + c] * B[c * 64 + d];
        W_comb[zl * 4096 + i] = acc * INV_AVG;
    }
}

// ---------------- K4: out[n] = msg[n] @ W_comb[elem(n)]  (in-place on d_out) ----------------
__global__ void __launch_bounds__(256) k_node_out(
    const float* __restrict__ node_attrs,  // (N,10) one-hot
    const float* __restrict__ W_comb,      // (10,4,64,64)
    float* __restrict__ out)               // (N,16,64), holds msg on entry
{
    __shared__ float Wz[4 * 4096];   // 64 KiB
    __shared__ float msg_s[1024];    // 4 KiB
    __shared__ int zz;
    int n = blockIdx.x;
    int tid = threadIdx.x;
    if (tid < NELEM && node_attrs[n * NELEM + tid] > 0.5f) zz = tid;
    for (int i = tid; i < 1024; i += 256) msg_s[i] = out[(size_t)n * 1024 + i];
    __syncthreads();
    const float* Wsrc = W_comb + (size_t)zz * 4 * 4096;
    for (int i = tid; i < 4 * 4096; i += 256) Wz[i] = Wsrc[i];
    __syncthreads();
#pragma unroll
    for (int j = 0; j < 4; ++j) {
        int idx = tid + j * 256;
        int lm = idx >> 6, d = idx & 63;
        int l = (lm >= 9) ? 3 : (lm >= 4) ? 2 : (lm >= 1) ? 1 : 0;
        const float* W = Wz + l * 4096;
        const float* m = msg_s + lm * 64;
        float acc = 0.f;
#pragma unroll
        for (int k = 0; k < 64; ++k) acc += m[k] * W[k * 64 + d];
        out[(size_t)n * 1024 + idx] = acc;
    }
}

extern "C" void kernel_launch(void* const* d_in, const int* in_sizes, int n_in,
                              void* d_out, int out_size, void* d_ws, size_t ws_size,
                              hipStream_t stream)
{
    const float* node_attrs = (const float*)d_in[0];   // (N,10)
    const float* node_feats = (const float*)d_in[1];   // (N,64)
    const float* edge_attrs = (const float*)d_in[2];   // (E,16)
    const float* edge_feats = (const float*)d_in[3];   // (E,256)
    const float* W_up       = (const float*)d_in[4];   // (64,64)
    const float* W_lin      = (const float*)d_in[5];   // (4,64,64)
    const float* W_skip     = (const float*)d_in[6];   // (10,4,64,64)
    const int*   edge_index = (const int*)d_in[7];     // (2,E)
    const int* sender   = edge_index;
    const int* receiver = edge_index + N_EDGES;
    float* out = (float*)d_out;

    // workspace layout: nf (N*64 f32), W_comb (10*4*64*64 f32)
    float* nf     = (float*)d_ws;
    float* W_comb = nf + (size_t)N_NODES * NCH;

    // zero the accumulation buffer (d_out) every call
    hipMemsetAsync(d_out, 0, (size_t)out_size * sizeof(float), stream);

    k_linear_up<<<(N_NODES + 3) / 4, 256, 0, stream>>>(node_feats, W_up, nf);
    k_wcomb<<<NELEM * 4, 256, 0, stream>>>(W_lin, W_skip, W_comb);
    k_edge_scatter<<<(N_EDGES + 3) / 4, 256, 0, stream>>>(
        nf, edge_attrs, edge_feats, sender, receiver, out);
    k_node_out<<<N_NODES, 256, 0, stream>>>(node_attrs, W_comb, out);
}

// Round 2
// 488.066 us; speedup vs baseline: 3.1144x; 3.1144x over previous
//
#include <hip/hip_runtime.h>

#define N_NODES 20000
#define N_EDGES 400000
#define NCH 64
#define NLM 16      // (LMAX+1)^2
#define NELEM 10
#define INV_AVG (1.0f / 20.0f)

// ---------------- K1: nf = node_feats @ W_up ----------------
__global__ void __launch_bounds__(256) k_linear_up(
    const float* __restrict__ node_feats,
    const float* __restrict__ W_up,
    float* __restrict__ nf)
{
    __shared__ float Ws[64 * 64];
    int tid = threadIdx.x;
    for (int i = tid; i < 64 * 64; i += 256) Ws[i] = W_up[i];
    __syncthreads();
    int n = blockIdx.x * 4 + (tid >> 6);
    if (n >= N_NODES) return;
    int c = tid & 63;
    const float* row = node_feats + n * 64;
    float acc = 0.f;
#pragma unroll
    for (int k = 0; k < 64; ++k) acc += row[k] * Ws[k * 64 + c];
    nf[n * 64 + c] = acc;
}

// ---------------- K2: W_comb[z,l] = W_lin[l] @ W_skip[z,l] / 20 ----------------
__global__ void __launch_bounds__(256) k_wcomb(
    const float* __restrict__ W_lin,   // (4,64,64)
    const float* __restrict__ W_skip,  // (10,4,64,64)
    float* __restrict__ W_comb)        // (10,4,64,64)
{
    __shared__ float A[64 * 64];
    __shared__ float B[64 * 64];
    int zl = blockIdx.x;           // z*4 + l
    int l = zl & 3;
    int tid = threadIdx.x;
    for (int i = tid; i < 4096; i += 256) {
        A[i] = W_lin[l * 4096 + i];
        B[i] = W_skip[zl * 4096 + i];
    }
    __syncthreads();
    for (int i = tid; i < 4096; i += 256) {
        int k = i >> 6, d = i & 63;
        float acc = 0.f;
#pragma unroll
        for (int c = 0; c < 64; ++c) acc += A[k * 64 + c] * B[c * 64 + d];
        W_comb[zl * 4096 + i] = acc * INV_AVG;
    }
}

// ---------------- CSR build ----------------
__global__ void __launch_bounds__(256) k_hist(
    const int* __restrict__ receiver, int* __restrict__ cnt)
{
    int e = blockIdx.x * 256 + threadIdx.x;
    if (e < N_EDGES) atomicAdd(&cnt[receiver[e]], 1);
}

// single-block exclusive scan over 20000 counts -> off[0..N], cursor copy
__global__ void __launch_bounds__(1024) k_scan(
    const int* __restrict__ cnt, int* __restrict__ off, int* __restrict__ cursor)
{
    __shared__ int buf[1024];
    __shared__ int carry;
    int tid = threadIdx.x;
    if (tid == 0) carry = 0;
    __syncthreads();
    for (int base = 0; base < N_NODES; base += 1024) {
        int i = base + tid;
        int v = (i < N_NODES) ? cnt[i] : 0;
        buf[tid] = v;
        __syncthreads();
        for (int d = 1; d < 1024; d <<= 1) {
            int t = 0;
            if (tid >= d) t = buf[tid - d];
            __syncthreads();
            if (tid >= d) buf[tid] += t;
            __syncthreads();
        }
        if (i < N_NODES) {
            int excl = carry + buf[tid] - v;
            off[i] = excl;
            cursor[i] = excl;
        }
        __syncthreads();
        if (tid == 1023) carry += buf[1023];
        __syncthreads();
    }
    if (tid == 0) off[N_NODES] = carry;   // == N_EDGES
}

__global__ void __launch_bounds__(256) k_scatter(
    const int* __restrict__ sender, const int* __restrict__ receiver,
    int* __restrict__ cursor,
    int* __restrict__ eids, int* __restrict__ esend)
{
    int e = blockIdx.x * 256 + threadIdx.x;
    if (e >= N_EDGES) return;
    int r = receiver[e];
    int p = atomicAdd(&cursor[r], 1);
    eids[p] = e;
    esend[p] = sender[e];
}

// ---------------- K3: per-node gather-accumulate (no atomics) ----------------
__global__ void __launch_bounds__(256) k_gather(
    const float* __restrict__ nf,           // (N,64)
    const float* __restrict__ edge_attrs,   // (E,16)
    const float* __restrict__ edge_feats,   // (E,256)
    const int* __restrict__ off,            // (N+1)
    const int* __restrict__ eids,           // (E) sorted by receiver
    const int* __restrict__ esend,          // (E) sender of sorted edge
    float* __restrict__ out)                // (N,16,64) = msg
{
    int node = blockIdx.x * 4 + (threadIdx.x >> 6);
    int lane = threadIdx.x & 63;
    if (node >= N_NODES) return;
    int beg = off[node], end = off[node + 1];

    float acc[16];
#pragma unroll
    for (int lm = 0; lm < 16; ++lm) acc[lm] = 0.f;

    for (int p = beg; p < end; ++p) {
        int e = eids[p];
        int s = esend[p];
        float sfv = nf[s * 64 + lane];
        const float* ef = edge_feats + (size_t)e * 256;
        float pr0 = sfv * ef[lane];
        float pr1 = sfv * ef[64 + lane];
        float pr2 = sfv * ef[128 + lane];
        float pr3 = sfv * ef[192 + lane];
        float shv = edge_attrs[e * 16 + (lane & 15)];
#pragma unroll
        for (int lm = 0; lm < 16; ++lm) {
            float pr = (lm >= 9) ? pr3 : (lm >= 4) ? pr2 : (lm >= 1) ? pr1 : pr0;
            acc[lm] += __shfl(shv, lm, 64) * pr;
        }
    }
    float* o = out + (size_t)node * 1024 + lane;
#pragma unroll
    for (int lm = 0; lm < 16; ++lm) o[lm * 64] = acc[lm];
}

// ---------------- K4: out[n] = msg[n] @ W_comb[elem(n)]  (in-place on d_out) ----------------
__global__ void __launch_bounds__(256) k_node_out(
    const float* __restrict__ node_attrs,  // (N,10) one-hot
    const float* __restrict__ W_comb,      // (10,4,64,64)
    float* __restrict__ out)               // (N,16,64), holds msg on entry
{
    __shared__ float Wz[4 * 4096];   // 64 KiB
    __shared__ float msg_s[1024];    // 4 KiB
    __shared__ int zz;
    int n = blockIdx.x;
    int tid = threadIdx.x;
    if (tid < NELEM && node_attrs[n * NELEM + tid] > 0.5f) zz = tid;
    for (int i = tid; i < 1024; i += 256) msg_s[i] = out[(size_t)n * 1024 + i];
    __syncthreads();
    const float* Wsrc = W_comb + (size_t)zz * 4 * 4096;
    for (int i = tid; i < 4 * 4096; i += 256) Wz[i] = Wsrc[i];
    __syncthreads();
#pragma unroll
    for (int j = 0; j < 4; ++j) {
        int idx = tid + j * 256;
        int lm = idx >> 6, d = idx & 63;
        int l = (lm >= 9) ? 3 : (lm >= 4) ? 2 : (lm >= 1) ? 1 : 0;
        const float* W = Wz + l * 4096;
        const float* m = msg_s + lm * 64;
        float acc = 0.f;
#pragma unroll
        for (int k = 0; k < 64; ++k) acc += m[k] * W[k * 64 + d];
        out[(size_t)n * 1024 + idx] = acc;
    }
}

extern "C" void kernel_launch(void* const* d_in, const int* in_sizes, int n_in,
                              void* d_out, int out_size, void* d_ws, size_t ws_size,
                              hipStream_t stream)
{
    const float* node_attrs = (const float*)d_in[0];   // (N,10)
    const float* node_feats = (const float*)d_in[1];   // (N,64)
    const float* edge_attrs = (const float*)d_in[2];   // (E,16)
    const float* edge_feats = (const float*)d_in[3];   // (E,256)
    const float* W_up       = (const float*)d_in[4];   // (64,64)
    const float* W_lin      = (const float*)d_in[5];   // (4,64,64)
    const float* W_skip     = (const float*)d_in[6];   // (10,4,64,64)
    const int*   edge_index = (const int*)d_in[7];     // (2,E)
    const int* sender   = edge_index;
    const int* receiver = edge_index + N_EDGES;
    float* out = (float*)d_out;

    // workspace layout (all 4-byte elements)
    float* nf     = (float*)d_ws;                       // N*64
    float* W_comb = nf + (size_t)N_NODES * NCH;         // 10*4*64*64
    int*   cnt    = (int*)(W_comb + NELEM * 4 * 64 * 64);  // N
    int*   off    = cnt + N_NODES;                      // N+1
    int*   cursor = off + N_NODES + 1;                  // N
    int*   eids   = cursor + N_NODES;                   // E
    int*   esend  = eids + N_EDGES;                     // E

    hipMemsetAsync(cnt, 0, N_NODES * sizeof(int), stream);

    k_linear_up<<<(N_NODES + 3) / 4, 256, 0, stream>>>(node_feats, W_up, nf);
    k_wcomb<<<NELEM * 4, 256, 0, stream>>>(W_lin, W_skip, W_comb);
    k_hist<<<(N_EDGES + 255) / 256, 256, 0, stream>>>(receiver, cnt);
    k_scan<<<1, 1024, 0, stream>>>(cnt, off, cursor);
    k_scatter<<<(N_EDGES + 255) / 256, 256, 0, stream>>>(sender, receiver, cursor, eids, esend);
    k_gather<<<(N_NODES + 3) / 4, 256, 0, stream>>>(
        nf, edge_attrs, edge_feats, off, eids, esend, out);
    k_node_out<<<N_NODES, 256, 0, stream>>>(node_attrs, W_comb, out);
}

// Round 3
// 351.131 us; speedup vs baseline: 4.3289x; 1.3900x over previous
//
#include <hip/hip_runtime.h>

#define N_NODES 20000
#define N_EDGES 400000
#define NCH 64
#define NLM 16      // (LMAX+1)^2
#define NELEM 10
#define INV_AVG (1.0f / 20.0f)
#define NCHUNK 79   // ceil(20000/256)

// ---------------- K1: nf = node_feats @ W_up ----------------
__global__ void __launch_bounds__(256) k_linear_up(
    const float* __restrict__ node_feats,
    const float* __restrict__ W_up,
    float* __restrict__ nf)
{
    __shared__ float Ws[64 * 64];
    int tid = threadIdx.x;
    for (int i = tid; i < 64 * 64; i += 256) Ws[i] = W_up[i];
    __syncthreads();
    int n = blockIdx.x * 4 + (tid >> 6);
    if (n >= N_NODES) return;
    int c = tid & 63;
    const float* row = node_feats + n * 64;
    float acc = 0.f;
#pragma unroll
    for (int k = 0; k < 64; ++k) acc += row[k] * Ws[k * 64 + c];
    nf[n * 64 + c] = acc;
}

// ---------------- K2: W_comb[z,l] = W_lin[l] @ W_skip[z,l] / 20 ----------------
__global__ void __launch_bounds__(256) k_wcomb(
    const float* __restrict__ W_lin,   // (4,64,64)
    const float* __restrict__ W_skip,  // (10,4,64,64)
    float* __restrict__ W_comb)        // (10,4,64,64)
{
    __shared__ float A[64 * 64];
    __shared__ float B[64 * 64];
    int zl = blockIdx.x;           // z*4 + l
    int l = zl & 3;
    int tid = threadIdx.x;
    for (int i = tid; i < 4096; i += 256) {
        A[i] = W_lin[l * 4096 + i];
        B[i] = W_skip[zl * 4096 + i];
    }
    __syncthreads();
    for (int i = tid; i < 4096; i += 256) {
        int k = i >> 6, d = i & 63;
        float acc = 0.f;
#pragma unroll
        for (int c = 0; c < 64; ++c) acc += A[k * 64 + c] * B[c * 64 + d];
        W_comb[zl * 4096 + i] = acc * INV_AVG;
    }
}

// ---------------- CSR build ----------------
__global__ void __launch_bounds__(256) k_hist(
    const int* __restrict__ receiver, int* __restrict__ cnt)
{
    int e = blockIdx.x * 256 + threadIdx.x;
    if (e < N_EDGES) atomicAdd(&cnt[receiver[e]], 1);
}

// single-block scan: each thread serially prefixes 20 elements, then one
// 1024-wide Hillis-Steele over the thread sums (10 steps, ~21 barriers total)
__global__ void __launch_bounds__(1024) k_scan(
    const int* __restrict__ cnt, int* __restrict__ off, int* __restrict__ cursor)
{
    __shared__ int sums[1024];
    int tid = threadIdx.x;
    int base = tid * 20;
    int loc[20];
    int s = 0;
#pragma unroll
    for (int j = 0; j < 20; ++j) {
        int i = base + j;
        int v = (i < N_NODES) ? cnt[i] : 0;
        loc[j] = s;       // exclusive prefix within thread
        s += v;
    }
    sums[tid] = s;
    __syncthreads();
    for (int d = 1; d < 1024; d <<= 1) {
        int t = (tid >= d) ? sums[tid - d] : 0;
        __syncthreads();
        sums[tid] += t;   // inclusive
        __syncthreads();
    }
    int tb = (tid > 0) ? sums[tid - 1] : 0;
#pragma unroll
    for (int j = 0; j < 20; ++j) {
        int i = base + j;
        if (i < N_NODES) { int e = tb + loc[j]; off[i] = e; cursor[i] = e; }
    }
    if (tid == 1023) off[N_NODES] = sums[1023];
}

__global__ void __launch_bounds__(256) k_scatter(
    const int* __restrict__ sender, const int* __restrict__ receiver,
    int* __restrict__ cursor,
    int* __restrict__ eids, int* __restrict__ esend)
{
    int e = blockIdx.x * 256 + threadIdx.x;
    if (e >= N_EDGES) return;
    int r = receiver[e];
    int p = atomicAdd(&cursor[r], 1);
    eids[p] = e;
    esend[p] = sender[e];
}

// ---------------- K3: per-node gather-accumulate, software-pipelined ----------------
__global__ void __launch_bounds__(256) k_gather(
    const float* __restrict__ nf,           // (N,64)
    const float* __restrict__ edge_attrs,   // (E,16)
    const float* __restrict__ edge_feats,   // (E,256)
    const int* __restrict__ off,            // (N+1)
    const int* __restrict__ eids,           // (E) sorted by receiver
    const int* __restrict__ esend,          // (E)
    float* __restrict__ out)                // (N,16,64) = msg
{
    int node = blockIdx.x * 4 + (threadIdx.x >> 6);
    int lane = threadIdx.x & 63;
    if (node >= N_NODES) return;
    int beg = off[node], end = off[node + 1];

    float acc[16];
#pragma unroll
    for (int lm = 0; lm < 16; ++lm) acc[lm] = 0.f;

    for (int b0 = beg; b0 < end; b0 += 64) {
        int nb = min(64, end - b0);
        // coalesced batch load of edge ids + senders for this wave
        int eb = (b0 + lane < end) ? eids[b0 + lane] : 0;
        int sb = (b0 + lane < end) ? esend[b0 + lane] : 0;

        // prologue: load edge 0
        int e = __shfl(eb, 0, 64);
        int s = __shfl(sb, 0, 64);
        const float* ef = edge_feats + (size_t)e * 256;
        float f0 = ef[lane], f1 = ef[64 + lane], f2 = ef[128 + lane], f3 = ef[192 + lane];
        float shv = edge_attrs[e * 16 + (lane & 15)];
        float sfv = nf[s * 64 + lane];

        for (int i = 0; i < nb; ++i) {
            float cf0 = f0, cf1 = f1, cf2 = f2, cf3 = f3, csh = shv, csf = sfv;
            if (i + 1 < nb) {
                int e2 = __shfl(eb, i + 1, 64);
                int s2 = __shfl(sb, i + 1, 64);
                const float* ef2 = edge_feats + (size_t)e2 * 256;
                f0 = ef2[lane]; f1 = ef2[64 + lane];
                f2 = ef2[128 + lane]; f3 = ef2[192 + lane];
                shv = edge_attrs[e2 * 16 + (lane & 15)];
                sfv = nf[s2 * 64 + lane];
            }
            float pr0 = csf * cf0, pr1 = csf * cf1, pr2 = csf * cf2, pr3 = csf * cf3;
#pragma unroll
            for (int lm = 0; lm < 16; ++lm) {
                float pr = (lm >= 9) ? pr3 : (lm >= 4) ? pr2 : (lm >= 1) ? pr1 : pr0;
                acc[lm] += __shfl(csh, lm, 64) * pr;
            }
        }
    }
    float* o = out + (size_t)node * 1024 + lane;
#pragma unroll
    for (int lm = 0; lm < 16; ++lm) o[lm * 64] = acc[lm];
}

// ---------------- K4: out[n] = msg[n] @ W_comb[elem(n)], W amortized per block ----------------
// grid: NELEM * NCHUNK blocks. Block (z, chunk): stages W_comb[z] once, processes
// all nodes in [chunk*256, chunk*256+256) whose element == z. In-place on d_out.
__global__ void __launch_bounds__(256) k_node_out(
    const float* __restrict__ node_attrs,  // (N,10) one-hot
    const float* __restrict__ W_comb,      // (10,4,64,64)
    float* __restrict__ out)               // (N,16,64), holds msg on entry
{
    __shared__ float Wz[4 * 4096];   // 64 KiB
    __shared__ float ms[2][1024];    // 8 KiB
    __shared__ int list[256];
    __shared__ int nmatch;
    int z = blockIdx.x / NCHUNK;
    int chunk = blockIdx.x % NCHUNK;
    int tid = threadIdx.x;

    const float* Wsrc = W_comb + (size_t)z * 16384;
    for (int i = tid; i < 16384; i += 256) Wz[i] = Wsrc[i];
    if (tid == 0) nmatch = 0;
    __syncthreads();

    int n = chunk * 256 + tid;
    if (n < N_NODES) {
        const float* a = node_attrs + (size_t)n * NELEM;
        int myz = 0;
#pragma unroll
        for (int j = 1; j < NELEM; ++j) if (a[j] > 0.5f) myz = j;
        if (myz == z) { int p = atomicAdd(&nmatch, 1); list[p] = n; }
    }
    __syncthreads();
    int cnt = nmatch;

    int lm = tid >> 4;             // 0..15
    int dq = (tid & 15) * 4;       // 0,4,...,60
    int l = (lm >= 9) ? 3 : (lm >= 4) ? 2 : (lm >= 1) ? 1 : 0;
    const float* W = Wz + l * 4096;

    for (int g = 0; g < cnt; g += 2) {
        int nA = list[g];
        int nB = (g + 1 < cnt) ? list[g + 1] : nA;
        const float* srcA = out + (size_t)nA * 1024;
        const float* srcB = out + (size_t)nB * 1024;
        for (int i = tid; i < 1024; i += 256) {
            ms[0][i] = srcA[i];
            ms[1][i] = srcB[i];
        }
        __syncthreads();

        float a0 = 0, a1 = 0, a2 = 0, a3 = 0, b0 = 0, b1 = 0, b2 = 0, b3 = 0;
#pragma unroll 8
        for (int k = 0; k < 64; ++k) {
            float4 w = *(const float4*)&W[k * 64 + dq];
            float mA = ms[0][lm * 64 + k];
            float mB = ms[1][lm * 64 + k];
            a0 += mA * w.x; a1 += mA * w.y; a2 += mA * w.z; a3 += mA * w.w;
            b0 += mB * w.x; b1 += mB * w.y; b2 += mB * w.z; b3 += mB * w.w;
        }
        __syncthreads();   // all reads of ms done before next-group overwrite

        float4* oA = (float4*)(out + (size_t)nA * 1024 + lm * 64 + dq);
        *oA = make_float4(a0, a1, a2, a3);
        if (g + 1 < cnt) {
            float4* oB = (float4*)(out + (size_t)nB * 1024 + lm * 64 + dq);
            *oB = make_float4(b0, b1, b2, b3);
        }
    }
}

extern "C" void kernel_launch(void* const* d_in, const int* in_sizes, int n_in,
                              void* d_out, int out_size, void* d_ws, size_t ws_size,
                              hipStream_t stream)
{
    const float* node_attrs = (const float*)d_in[0];   // (N,10)
    const float* node_feats = (const float*)d_in[1];   // (N,64)
    const float* edge_attrs = (const float*)d_in[2];   // (E,16)
    const float* edge_feats = (const float*)d_in[3];   // (E,256)
    const float* W_up       = (const float*)d_in[4];   // (64,64)
    const float* W_lin      = (const float*)d_in[5];   // (4,64,64)
    const float* W_skip     = (const float*)d_in[6];   // (10,4,64,64)
    const int*   edge_index = (const int*)d_in[7];     // (2,E)
    const int* sender   = edge_index;
    const int* receiver = edge_index + N_EDGES;
    float* out = (float*)d_out;

    // workspace layout (all 4-byte elements)
    float* nf     = (float*)d_ws;                       // N*64
    float* W_comb = nf + (size_t)N_NODES * NCH;         // 10*4*64*64
    int*   cnt    = (int*)(W_comb + NELEM * 4 * 64 * 64);  // N
    int*   off    = cnt + N_NODES;                      // N+1
    int*   cursor = off + N_NODES + 1;                  // N
    int*   eids   = cursor + N_NODES;                   // E
    int*   esend  = eids + N_EDGES;                     // E

    hipMemsetAsync(cnt, 0, N_NODES * sizeof(int), stream);

    k_linear_up<<<(N_NODES + 3) / 4, 256, 0, stream>>>(node_feats, W_up, nf);
    k_wcomb<<<NELEM * 4, 256, 0, stream>>>(W_lin, W_skip, W_comb);
    k_hist<<<(N_EDGES + 255) / 256, 256, 0, stream>>>(receiver, cnt);
    k_scan<<<1, 1024, 0, stream>>>(cnt, off, cursor);
    k_scatter<<<(N_EDGES + 255) / 256, 256, 0, stream>>>(sender, receiver, cursor, eids, esend);
    k_gather<<<(N_NODES + 3) / 4, 256, 0, stream>>>(
        nf, edge_attrs, edge_feats, off, eids, esend, out);
    k_node_out<<<NELEM * NCHUNK, 256, 0, stream>>>(node_attrs, W_comb, out);
}

// Round 4
// 342.149 us; speedup vs baseline: 4.4425x; 1.0262x over previous
//
#include <hip/hip_runtime.h>

#define N_NODES 20000
#define N_EDGES 400000
#define NCH 64
#define NELEM 10
#define INV_AVG (1.0f / 20.0f)
#define NCHUNK 79   // ceil(20000/256)

__device__ __forceinline__ float rlanef(float v, int l) {
    return __int_as_float(__builtin_amdgcn_readlane(__float_as_int(v), l));
}
__device__ __forceinline__ int rlanei(int v, int l) {
    return __builtin_amdgcn_readlane(v, l);
}

// ---------------- K1: nf = node_feats @ W_up ----------------
__global__ void __launch_bounds__(256) k_linear_up(
    const float* __restrict__ node_feats,
    const float* __restrict__ W_up,
    float* __restrict__ nf)
{
    __shared__ float Ws[64 * 64];
    int tid = threadIdx.x;
    for (int i = tid; i < 64 * 64; i += 256) Ws[i] = W_up[i];
    __syncthreads();
    int n = blockIdx.x * 4 + (tid >> 6);
    if (n >= N_NODES) return;
    int c = tid & 63;
    const float* row = node_feats + n * 64;
    float acc = 0.f;
#pragma unroll
    for (int k = 0; k < 64; ++k) acc += row[k] * Ws[k * 64 + c];
    nf[n * 64 + c] = acc;
}

// ---------------- K2: W_comb[z,l] = W_lin[l] @ W_skip[z,l] / 20 ----------------
__global__ void __launch_bounds__(256) k_wcomb(
    const float* __restrict__ W_lin,   // (4,64,64)
    const float* __restrict__ W_skip,  // (10,4,64,64)
    float* __restrict__ W_comb)        // (10,4,64,64)
{
    __shared__ float A[64 * 64];
    __shared__ float B[64 * 64];
    int zl = blockIdx.x;           // z*4 + l
    int l = zl & 3;
    int tid = threadIdx.x;
    for (int i = tid; i < 4096; i += 256) {
        A[i] = W_lin[l * 4096 + i];
        B[i] = W_skip[zl * 4096 + i];
    }
    __syncthreads();
    for (int i = tid; i < 4096; i += 256) {
        int k = i >> 6, d = i & 63;
        float acc = 0.f;
#pragma unroll
        for (int c = 0; c < 64; ++c) acc += A[k * 64 + c] * B[c * 64 + d];
        W_comb[zl * 4096 + i] = acc * INV_AVG;
    }
}

// ---------------- CSR build ----------------
__global__ void __launch_bounds__(256) k_hist(
    const int* __restrict__ receiver, int* __restrict__ cnt)
{
    int e = blockIdx.x * 256 + threadIdx.x;
    if (e < N_EDGES) atomicAdd(&cnt[receiver[e]], 1);
}

__global__ void __launch_bounds__(1024) k_scan(
    const int* __restrict__ cnt, int* __restrict__ off, int* __restrict__ cursor)
{
    __shared__ int sums[1024];
    int tid = threadIdx.x;
    int base = tid * 20;
    int loc[20];
    int s = 0;
#pragma unroll
    for (int j = 0; j < 20; ++j) {
        int i = base + j;
        int v = (i < N_NODES) ? cnt[i] : 0;
        loc[j] = s;
        s += v;
    }
    sums[tid] = s;
    __syncthreads();
    for (int d = 1; d < 1024; d <<= 1) {
        int t = (tid >= d) ? sums[tid - d] : 0;
        __syncthreads();
        sums[tid] += t;
        __syncthreads();
    }
    int tb = (tid > 0) ? sums[tid - 1] : 0;
#pragma unroll
    for (int j = 0; j < 20; ++j) {
        int i = base + j;
        if (i < N_NODES) { int e = tb + loc[j]; off[i] = e; cursor[i] = e; }
    }
    if (tid == 1023) off[N_NODES] = sums[1023];
}

__global__ void __launch_bounds__(256) k_scatter(
    const int* __restrict__ sender, const int* __restrict__ receiver,
    int* __restrict__ cursor, int2* __restrict__ epack)
{
    int e = blockIdx.x * 256 + threadIdx.x;
    if (e >= N_EDGES) return;
    int r = receiver[e];
    int p = atomicAdd(&cursor[r], 1);
    epack[p] = make_int2(e, sender[e]);
}

// ---------------- K3: per-node gather, readlane broadcast + 2-slot pipeline ----------------
__global__ void __launch_bounds__(256) k_gather(
    const float* __restrict__ nf,           // (N,64)
    const float* __restrict__ edge_attrs,   // (E,16)
    const float* __restrict__ edge_feats,   // (E,256)
    const int* __restrict__ off,            // (N+1)
    const int2* __restrict__ epack,         // (E) (eid, sender) sorted by receiver
    float* __restrict__ out)                // (N,16,64) = msg
{
    int node = blockIdx.x * 4 + (threadIdx.x >> 6);
    int lane = threadIdx.x & 63;
    if (node >= N_NODES) return;
    int beg = off[node], end = off[node + 1];

    float acc[16];
#pragma unroll
    for (int lm = 0; lm < 16; ++lm) acc[lm] = 0.f;

    for (int b0 = beg; b0 < end; b0 += 64) {
        int nb = min(64, end - b0);
        int2 ep = (b0 + lane < end) ? epack[b0 + lane] : make_int2(0, 0);
        int eb = ep.x, sb = ep.y;

        float f0a, f1a, f2a, f3a, sha, sfa;
        float f0b, f1b, f2b, f3b, shb, sfb;

        // prologue: fill slot A (edge 0), slot B (edge 1)
        {
            int e = rlanei(eb, 0), s = rlanei(sb, 0);
            const float* ef = edge_feats + (size_t)e * 256;
            f0a = ef[lane]; f1a = ef[64 + lane]; f2a = ef[128 + lane]; f3a = ef[192 + lane];
            sha = edge_attrs[(size_t)e * 16 + (lane & 15)];
            sfa = nf[(size_t)s * 64 + lane];
        }
        if (nb > 1) {
            int e = rlanei(eb, 1), s = rlanei(sb, 1);
            const float* ef = edge_feats + (size_t)e * 256;
            f0b = ef[lane]; f1b = ef[64 + lane]; f2b = ef[128 + lane]; f3b = ef[192 + lane];
            shb = edge_attrs[(size_t)e * 16 + (lane & 15)];
            sfb = nf[(size_t)s * 64 + lane];
        }

        for (int i = 0; i < nb; i += 2) {
            // ---- compute edge i (slot A) ----
            {
                float pr0 = sfa * f0a, pr1 = sfa * f1a, pr2 = sfa * f2a, pr3 = sfa * f3a;
                acc[0] += rlanef(sha, 0) * pr0;
#pragma unroll
                for (int lm = 1; lm < 4; ++lm)  acc[lm] += rlanef(sha, lm) * pr1;
#pragma unroll
                for (int lm = 4; lm < 9; ++lm)  acc[lm] += rlanef(sha, lm) * pr2;
#pragma unroll
                for (int lm = 9; lm < 16; ++lm) acc[lm] += rlanef(sha, lm) * pr3;
            }
            // ---- refill slot A with edge i+2 ----
            if (i + 2 < nb) {
                int e = rlanei(eb, i + 2), s = rlanei(sb, i + 2);
                const float* ef = edge_feats + (size_t)e * 256;
                f0a = ef[lane]; f1a = ef[64 + lane]; f2a = ef[128 + lane]; f3a = ef[192 + lane];
                sha = edge_attrs[(size_t)e * 16 + (lane & 15)];
                sfa = nf[(size_t)s * 64 + lane];
            }
            // ---- compute edge i+1 (slot B) ----
            if (i + 1 < nb) {
                float pr0 = sfb * f0b, pr1 = sfb * f1b, pr2 = sfb * f2b, pr3 = sfb * f3b;
                acc[0] += rlanef(shb, 0) * pr0;
#pragma unroll
                for (int lm = 1; lm < 4; ++lm)  acc[lm] += rlanef(shb, lm) * pr1;
#pragma unroll
                for (int lm = 4; lm < 9; ++lm)  acc[lm] += rlanef(shb, lm) * pr2;
#pragma unroll
                for (int lm = 9; lm < 16; ++lm) acc[lm] += rlanef(shb, lm) * pr3;
            }
            // ---- refill slot B with edge i+3 ----
            if (i + 3 < nb) {
                int e = rlanei(eb, i + 3), s = rlanei(sb, i + 3);
                const float* ef = edge_feats + (size_t)e * 256;
                f0b = ef[lane]; f1b = ef[64 + lane]; f2b = ef[128 + lane]; f3b = ef[192 + lane];
                shb = edge_attrs[(size_t)e * 16 + (lane & 15)];
                sfb = nf[(size_t)s * 64 + lane];
            }
        }
    }
    float* o = out + (size_t)node * 1024 + lane;
#pragma unroll
    for (int lm = 0; lm < 16; ++lm) o[lm * 64] = acc[lm];
}

// ---------------- K4: out[n] = msg[n] @ W_comb[elem(n)], W amortized per block ----------------
__global__ void __launch_bounds__(256) k_node_out(
    const float* __restrict__ node_attrs,  // (N,10) one-hot
    const float* __restrict__ W_comb,      // (10,4,64,64)
    float* __restrict__ out)               // (N,16,64), holds msg on entry
{
    __shared__ float Wz[4 * 4096];   // 64 KiB
    __shared__ float ms[2][1024];    // 8 KiB
    __shared__ int list[256];
    __shared__ int nmatch;
    int z = blockIdx.x / NCHUNK;
    int chunk = blockIdx.x % NCHUNK;
    int tid = threadIdx.x;

    const float* Wsrc = W_comb + (size_t)z * 16384;
    for (int i = tid; i < 16384; i += 256) Wz[i] = Wsrc[i];
    if (tid == 0) nmatch = 0;
    __syncthreads();

    int n = chunk * 256 + tid;
    if (n < N_NODES) {
        const float* a = node_attrs + (size_t)n * NELEM;
        int myz = 0;
#pragma unroll
        for (int j = 1; j < NELEM; ++j) if (a[j] > 0.5f) myz = j;
        if (myz == z) { int p = atomicAdd(&nmatch, 1); list[p] = n; }
    }
    __syncthreads();
    int cnt = nmatch;

    int lm = tid >> 4;             // 0..15
    int dq = (tid & 15) * 4;       // 0,4,...,60
    int l = (lm >= 9) ? 3 : (lm >= 4) ? 2 : (lm >= 1) ? 1 : 0;
    const float* W = Wz + l * 4096;

    for (int g = 0; g < cnt; g += 2) {
        int nA = list[g];
        int nB = (g + 1 < cnt) ? list[g + 1] : nA;
        const float* srcA = out + (size_t)nA * 1024;
        const float* srcB = out + (size_t)nB * 1024;
        for (int i = tid; i < 1024; i += 256) {
            ms[0][i] = srcA[i];
            ms[1][i] = srcB[i];
        }
        __syncthreads();

        float a0 = 0, a1 = 0, a2 = 0, a3 = 0, b0 = 0, b1 = 0, b2 = 0, b3 = 0;
#pragma unroll 8
        for (int k = 0; k < 64; ++k) {
            float4 w = *(const float4*)&W[k * 64 + dq];
            float mA = ms[0][lm * 64 + k];
            float mB = ms[1][lm * 64 + k];
            a0 += mA * w.x; a1 += mA * w.y; a2 += mA * w.z; a3 += mA * w.w;
            b0 += mB * w.x; b1 += mB * w.y; b2 += mB * w.z; b3 += mB * w.w;
        }
        __syncthreads();

        float4* oA = (float4*)(out + (size_t)nA * 1024 + lm * 64 + dq);
        *oA = make_float4(a0, a1, a2, a3);
        if (g + 1 < cnt) {
            float4* oB = (float4*)(out + (size_t)nB * 1024 + lm * 64 + dq);
            *oB = make_float4(b0, b1, b2, b3);
        }
    }
}

extern "C" void kernel_launch(void* const* d_in, const int* in_sizes, int n_in,
                              void* d_out, int out_size, void* d_ws, size_t ws_size,
                              hipStream_t stream)
{
    const float* node_attrs = (const float*)d_in[0];   // (N,10)
    const float* node_feats = (const float*)d_in[1];   // (N,64)
    const float* edge_attrs = (const float*)d_in[2];   // (E,16)
    const float* edge_feats = (const float*)d_in[3];   // (E,256)
    const float* W_up       = (const float*)d_in[4];   // (64,64)
    const float* W_lin      = (const float*)d_in[5];   // (4,64,64)
    const float* W_skip     = (const float*)d_in[6];   // (10,4,64,64)
    const int*   edge_index = (const int*)d_in[7];     // (2,E)
    const int* sender   = edge_index;
    const int* receiver = edge_index + N_EDGES;
    float* out = (float*)d_out;

    // workspace layout: epack first for 8-byte alignment
    int2*  epack  = (int2*)d_ws;                        // E int2
    float* nf     = (float*)(epack + N_EDGES);          // N*64
    float* W_comb = nf + (size_t)N_NODES * NCH;         // 10*4*64*64
    int*   cnt    = (int*)(W_comb + NELEM * 4 * 64 * 64);  // N
    int*   off    = cnt + N_NODES;                      // N+1
    int*   cursor = off + N_NODES + 1;                  // N

    hipMemsetAsync(cnt, 0, N_NODES * sizeof(int), stream);

    k_linear_up<<<(N_NODES + 3) / 4, 256, 0, stream>>>(node_feats, W_up, nf);
    k_wcomb<<<NELEM * 4, 256, 0, stream>>>(W_lin, W_skip, W_comb);
    k_hist<<<(N_EDGES + 255) / 256, 256, 0, stream>>>(receiver, cnt);
    k_scan<<<1, 1024, 0, stream>>>(cnt, off, cursor);
    k_scatter<<<(N_EDGES + 255) / 256, 256, 0, stream>>>(sender, receiver, cursor, epack);
    k_gather<<<(N_NODES + 3) / 4, 256, 0, stream>>>(
        nf, edge_attrs, edge_feats, off, epack, out);
    k_node_out<<<NELEM * NCHUNK, 256, 0, stream>>>(node_attrs, W_comb, out);
}